// Round 5
// baseline (597.713 us; speedup 1.0000x reference)
//
#include <hip/hip_runtime.h>

#define INCH 128
#define C1   16
#define C2   64

typedef int iv4 __attribute__((ext_vector_type(4)));
typedef unsigned short usv8 __attribute__((ext_vector_type(8)));

// bf16 helpers: RTNE store, shift load
__device__ __forceinline__ unsigned short f2bf(float f) {
    unsigned u = __float_as_uint(f);
    return (unsigned short)((u + 0x7FFF + ((u >> 16) & 1)) >> 16);
}
__device__ __forceinline__ float bf2f(unsigned short s) {
    return __uint_as_float((unsigned)s << 16);
}

// ---------------- init: zero deg + zero pad-source rows --------------------
__global__ __launch_bounds__(256) void init_kernel(
    int* __restrict__ deg, int n, int* __restrict__ xz, int* __restrict__ hz)
{
    int t = blockIdx.x * blockDim.x + threadIdx.x;
    if (t < n) deg[t] = 0;
    if (t < 8) { xz[t] = 0; hz[t] = 0; }   // row n of xW1s_bf / hs_bf = 0
}

// ---------------- degree histogram via global atomics ----------------------
// 3.2M no-return atomicAdds spread over 100K counters (~32/addr) — pipelined.
__global__ __launch_bounds__(256) void deg_kernel(
    const int* __restrict__ row, const int* __restrict__ col,
    int* __restrict__ deg, int e, int n)
{
    int e4 = e >> 2;
    const iv4* c4p = (const iv4*)col;
    const iv4* r4p = (const iv4*)row;
    int stride = gridDim.x * blockDim.x;
    for (int i = blockIdx.x * blockDim.x + threadIdx.x; i < e4; i += stride) {
        iv4 c4 = c4p[i], r4 = r4p[i];
        #pragma unroll
        for (int k = 0; k < 4; ++k) {
            unsigned c = (unsigned)c4[k], r = (unsigned)r4[k];
            if (c < (unsigned)n && r < (unsigned)n)
                atomicAdd(&deg[c], 1);
        }
    }
    if (blockIdx.x == 0) {                          // tail (e % 4)
        for (int i = e4 * 4 + threadIdx.x; i < e; i += 256) {
            unsigned c = (unsigned)col[i], r = (unsigned)row[i];
            if (c < (unsigned)n && r < (unsigned)n)
                atomicAdd(&deg[c], 1);
        }
    }
}

// ---------------- scan1: per-1024-node block exclusive scan of padded deg --
__global__ __launch_bounds__(1024) void scan1_kernel(
    const int* __restrict__ deg, int* __restrict__ offs,
    int* __restrict__ btot, int n)
{
    __shared__ int tmp[1024];
    int tid = threadIdx.x;
    int node = blockIdx.x * 1024 + tid;
    int d  = (node < n) ? deg[node] : 0;
    int pc = (d + 3) & ~3;                 // 4-padded per-node count
    tmp[tid] = pc;
    __syncthreads();
    for (int off = 1; off < 1024; off <<= 1) {
        int v = (tid >= off) ? tmp[tid - off] : 0;
        __syncthreads();
        tmp[tid] += v;
        __syncthreads();
    }
    if (node < n) offs[node] = tmp[tid] - pc;       // local exclusive
    if (tid == 1023) btot[blockIdx.x] = tmp[1023];  // block total
}

// ---------------- scan2: serial scan of ~98 block totals -------------------
__global__ void scan2_kernel(int* __restrict__ btot, int nb) {
    if (blockIdx.x == 0 && threadIdx.x == 0) {
        int s = 0;
        for (int i = 0; i < nb; ++i) { int v = btot[i]; btot[i] = s; s += v; }
    }
}

// ---------------- scan3: finalize offs/cur/inv, fill pad slots -------------
__global__ __launch_bounds__(1024) void scan3_kernel(
    const int* __restrict__ deg, int* __restrict__ offs, int* __restrict__ cur,
    float* __restrict__ inv, int* __restrict__ sorted,
    const int* __restrict__ btot, int n)
{
    int node = blockIdx.x * 1024 + threadIdx.x;
    if (node >= n) return;
    int o = offs[node] + btot[blockIdx.x];
    offs[node] = o;
    cur[node]  = o;
    int d = deg[node], pc = (d + 3) & ~3;
    for (int j = d; j < pc; ++j) sorted[o + j] = n;  // pad -> zero-source row
    inv[node] = rsqrtf((float)(d + 1));
}

// ---------------- scatter: direct CSR fill via global atomics --------------
__global__ __launch_bounds__(256) void scatter_kernel(
    const int* __restrict__ row, const int* __restrict__ col,
    int* __restrict__ cur, int* __restrict__ sorted, int e, int n, int cap)
{
    int e4 = e >> 2;
    const iv4* c4p = (const iv4*)col;
    const iv4* r4p = (const iv4*)row;
    int stride = gridDim.x * blockDim.x;
    for (int i = blockIdx.x * blockDim.x + threadIdx.x; i < e4; i += stride) {
        iv4 c4 = c4p[i], r4 = r4p[i];
        #pragma unroll
        for (int k = 0; k < 4; ++k) {
            unsigned c = (unsigned)c4[k], r = (unsigned)r4[k];
            if (c < (unsigned)n && r < (unsigned)n) {
                int pos = atomicAdd(&cur[c], 1);
                if ((unsigned)pos < (unsigned)cap) sorted[pos] = (int)r;
            }
        }
    }
    if (blockIdx.x == 0) {
        for (int i = e4 * 4 + threadIdx.x; i < e; i += 256) {
            unsigned c = (unsigned)col[i], r = (unsigned)row[i];
            if (c < (unsigned)n && r < (unsigned)n) {
                int pos = atomicAdd(&cur[c], 1);
                if ((unsigned)pos < (unsigned)cap) sorted[pos] = (int)r;
            }
        }
    }
}

// ---------------- linear1: xW1s_bf = bf16((x@W1)*inv), xT1 = x@t1_W + t1_b -
__global__ __launch_bounds__(256) void linear1_kernel(
    const float* __restrict__ x, const float* __restrict__ W1,
    const float* __restrict__ T1, const float* __restrict__ t1b,
    const float* __restrict__ inv,
    unsigned short* __restrict__ xW1s_bf, float* __restrict__ xT1, int n)
{
    __shared__ float Wc[INCH][32];        // [:,0:16]=W1, [:,16:32]=t1_W
    __shared__ float xs[16][INCH + 4];
    int tid = threadIdx.x;

    for (int i = tid; i < INCH * C1; i += 256) {
        int k = i / C1, c = i % C1;
        Wc[k][c]      = W1[i];
        Wc[k][c + 16] = T1[i];
    }
    int node0 = blockIdx.x * 16;
    for (int i = tid; i < 16 * (INCH / 4); i += 256) {
        int r = i / (INCH / 4);
        int cc = i % (INCH / 4);
        int node = node0 + r;
        float4 v = make_float4(0.f, 0.f, 0.f, 0.f);
        if (node < n) v = ((const float4*)x)[(size_t)node * (INCH / 4) + cc];
        ((float4*)&xs[r][0])[cc] = v;
    }
    __syncthreads();

    int ch = tid & 15, nl = tid >> 4;
    int node = node0 + nl;
    if (node >= n) return;
    float a1 = 0.f, a2 = 0.f;
    #pragma unroll
    for (int k = 0; k < INCH; ++k) {
        float xv = xs[nl][k];
        a1 += xv * Wc[k][ch];
        a2 += xv * Wc[k][ch + 16];
    }
    xW1s_bf[(node << 4) + ch] = f2bf(a1 * inv[node]);  // pre-scaled by inv[src]
    xT1[(node << 4) + ch]     = a2 + t1b[ch];
}

// ---- gather core: 4 lanes/node (2 edge-chunk-parities x 2 channel-halves).
//      Lane pr handles 4 CONSECUTIVE edges per 8 (aligned dwordx4 index load
//      + 4 ushort8 gathers), register accumulation, shfl_xor(2) combine.
//      Segments are 4-padded with zero-source index n -> no tail loop.
#define GATHER_ACC(SRCBUF)                                                    \
    float a0 = 0.f, a1 = 0.f, a2 = 0.f, a3 = 0.f,                             \
          a4 = 0.f, a5 = 0.f, a6 = 0.f, a7 = 0.f;                             \
    {                                                                         \
        int p  = beg + (pr << 2);                                             \
        int pe = beg + m;                                                     \
        for (; p + 3 < pe; p += 8) {                                          \
            iv4 s4 = *(const iv4*)(sorted + p);          /* 16B aligned */    \
            usv8 v0 = *(const usv8*)(SRCBUF + ((size_t)(unsigned)s4[0] << 4) + chb); \
            usv8 v1 = *(const usv8*)(SRCBUF + ((size_t)(unsigned)s4[1] << 4) + chb); \
            usv8 v2 = *(const usv8*)(SRCBUF + ((size_t)(unsigned)s4[2] << 4) + chb); \
            usv8 v3 = *(const usv8*)(SRCBUF + ((size_t)(unsigned)s4[3] << 4) + chb); \
            a0 += bf2f(v0[0]) + bf2f(v1[0]) + bf2f(v2[0]) + bf2f(v3[0]);      \
            a1 += bf2f(v0[1]) + bf2f(v1[1]) + bf2f(v2[1]) + bf2f(v3[1]);      \
            a2 += bf2f(v0[2]) + bf2f(v1[2]) + bf2f(v2[2]) + bf2f(v3[2]);      \
            a3 += bf2f(v0[3]) + bf2f(v1[3]) + bf2f(v2[3]) + bf2f(v3[3]);      \
            a4 += bf2f(v0[4]) + bf2f(v1[4]) + bf2f(v2[4]) + bf2f(v3[4]);      \
            a5 += bf2f(v0[5]) + bf2f(v1[5]) + bf2f(v2[5]) + bf2f(v3[5]);      \
            a6 += bf2f(v0[6]) + bf2f(v1[6]) + bf2f(v2[6]) + bf2f(v3[6]);      \
            a7 += bf2f(v0[7]) + bf2f(v1[7]) + bf2f(v2[7]) + bf2f(v3[7]);      \
        }                                                                     \
    }                                                                         \
    a0 += __shfl_xor(a0, 2); a1 += __shfl_xor(a1, 2);                         \
    a2 += __shfl_xor(a2, 2); a3 += __shfl_xor(a3, 2);                         \
    a4 += __shfl_xor(a4, 2); a5 += __shfl_xor(a5, 2);                         \
    a6 += __shfl_xor(a6, 2); a7 += __shfl_xor(a7, 2);

// ---------------- agg1 CSR: register gather + fused epilogue1 --------------
// 64 nodes/block, 256 threads: node = blk*64 + tid/4; lane quad = {parity, chb}
__global__ __launch_bounds__(256) void agg1_csr_kernel(
    const int* __restrict__ sorted, const int* __restrict__ offs,
    const int* __restrict__ cnt, const float* __restrict__ inv,
    const unsigned short* __restrict__ xW1s_bf, const float* __restrict__ xT1,
    const float* __restrict__ b1,
    float* __restrict__ h, unsigned short* __restrict__ hs_bf, int n)
{
    int tid = threadIdx.x;
    int node = blockIdx.x * 64 + (tid >> 2);
    int pr  = (tid >> 1) & 1;        // edge-chunk parity
    int chb = (tid & 1) << 3;        // channel half: 0..7 / 8..15
    int beg = 0, m = 0;
    if (node < n) { beg = offs[node]; m = (cnt[node] + 3) & ~3; }

    GATHER_ACC(xW1s_bf)

    if (node >= n || pr != 0) return;     // quad-uniform wrt shfl partners
    size_t idx = ((size_t)node << 4) + chb;
    usv8 selfv = *(const usv8*)(xW1s_bf + idx);
    float ic = inv[node];
    float hv0 = fmaxf((a0 + bf2f(selfv[0])) * ic + b1[chb + 0], 0.f) + xT1[idx + 0];
    float hv1 = fmaxf((a1 + bf2f(selfv[1])) * ic + b1[chb + 1], 0.f) + xT1[idx + 1];
    float hv2 = fmaxf((a2 + bf2f(selfv[2])) * ic + b1[chb + 2], 0.f) + xT1[idx + 2];
    float hv3 = fmaxf((a3 + bf2f(selfv[3])) * ic + b1[chb + 3], 0.f) + xT1[idx + 3];
    float hv4 = fmaxf((a4 + bf2f(selfv[4])) * ic + b1[chb + 4], 0.f) + xT1[idx + 4];
    float hv5 = fmaxf((a5 + bf2f(selfv[5])) * ic + b1[chb + 5], 0.f) + xT1[idx + 5];
    float hv6 = fmaxf((a6 + bf2f(selfv[6])) * ic + b1[chb + 6], 0.f) + xT1[idx + 6];
    float hv7 = fmaxf((a7 + bf2f(selfv[7])) * ic + b1[chb + 7], 0.f) + xT1[idx + 7];
    ((float4*)(h + idx))[0] = make_float4(hv0, hv1, hv2, hv3);
    ((float4*)(h + idx))[1] = make_float4(hv4, hv5, hv6, hv7);
    usv8 hb;
    hb[0] = f2bf(hv0 * ic); hb[1] = f2bf(hv1 * ic);
    hb[2] = f2bf(hv2 * ic); hb[3] = f2bf(hv3 * ic);
    hb[4] = f2bf(hv4 * ic); hb[5] = f2bf(hv5 * ic);
    hb[6] = f2bf(hv6 * ic); hb[7] = f2bf(hv7 * ic);
    *(usv8*)(hs_bf + idx) = hb;
}

// ---------------- agg2: register gather + fused 16->64 linears -------------
// 64 nodes/block. Gather into regs, plain LDS stores (exclusive), matmul epi.
__global__ __launch_bounds__(256) void agg2_fused_kernel(
    const int* __restrict__ sorted, const int* __restrict__ offs,
    const int* __restrict__ cnt, const float* __restrict__ inv,
    const unsigned short* __restrict__ hs_bf, const float* __restrict__ h,
    const float* __restrict__ W2, const float* __restrict__ T2,
    const float* __restrict__ b2, const float* __restrict__ t2b,
    float* __restrict__ out, int n)
{
    __shared__ float Wc[C1][128];     // [:,0:64]=W2, [:,64:128]=t2_W (8 KB)
    __shared__ float acc_s[64][C1];   // aggregated (incl. self, *ic)   (4 KB)
    __shared__ float h_s[64][C1];     // unscaled h for identity2       (4 KB)
    int tid = threadIdx.x;

    for (int i = tid; i < C1 * 128; i += 256) {
        int k = i >> 7, c = i & 127;
        Wc[k][c] = (c < 64) ? W2[k * C2 + c] : T2[k * C2 + (c - 64)];
    }
    {   // stage h rows (contiguous across the block -> coalesced float4)
        int node0 = blockIdx.x * 64;
        if (tid < 256) {
            float4 v = make_float4(0.f, 0.f, 0.f, 0.f);
            if (node0 + (tid >> 2) < n)
                v = ((const float4*)h)[(size_t)node0 * 4 + tid];
            ((float4*)&h_s[0][0])[tid] = v;
        }
    }

    int node = blockIdx.x * 64 + (tid >> 2);
    int pr  = (tid >> 1) & 1;
    int chb = (tid & 1) << 3;
    int beg = 0, m = 0;
    if (node < n) { beg = offs[node]; m = (cnt[node] + 3) & ~3; }

    GATHER_ACC(hs_bf)

    if (node < n && pr == 0) {
        size_t idx = ((size_t)node << 4) + chb;
        usv8 selfv = *(const usv8*)(hs_bf + idx);
        float ic = inv[node];
        int loc = tid >> 2;
        float4* ap = (float4*)&acc_s[loc][chb];
        ap[0] = make_float4((a0 + bf2f(selfv[0])) * ic, (a1 + bf2f(selfv[1])) * ic,
                            (a2 + bf2f(selfv[2])) * ic, (a3 + bf2f(selfv[3])) * ic);
        ap[1] = make_float4((a4 + bf2f(selfv[4])) * ic, (a5 + bf2f(selfv[5])) * ic,
                            (a6 + bf2f(selfv[6])) * ic, (a7 + bf2f(selfv[7])) * ic);
    }
    __syncthreads();

    // 16->64 matmuls: weights hoisted to registers, acc/h_s broadcast reads
    int och = tid & 63, g = tid >> 6;        // wave g handles locs [16g, 16g+16)
    float w1r[C1], w2r[C1];
    #pragma unroll
    for (int k = 0; k < C1; ++k) { w1r[k] = Wc[k][och]; w2r[k] = Wc[k][och + 64]; }
    float bb = b2[och], tb = t2b[och];
    for (int q = 0; q < 16; ++q) {
        int loc = (g << 4) + q;
        int node2 = blockIdx.x * 64 + loc;
        if (node2 >= n) continue;
        float s1 = bb, s2 = tb;
        #pragma unroll
        for (int k = 0; k < C1; ++k) {
            s1 += acc_s[loc][k] * w1r[k];
            s2 += h_s[loc][k]   * w2r[k];
        }
        out[(size_t)node2 * C2 + och] = fmaxf(s1, 0.f) + s2;
    }
}

extern "C" void kernel_launch(void* const* d_in, const int* in_sizes, int n_in,
                              void* d_out, int out_size, void* d_ws, size_t ws_size,
                              hipStream_t stream) {
    const float* x   = (const float*)d_in[0];
    const int*   ei  = (const int*)d_in[1];
    const float* W1  = (const float*)d_in[2];
    const float* b1  = (const float*)d_in[3];
    const float* W2  = (const float*)d_in[4];
    const float* b2  = (const float*)d_in[5];
    const float* T1  = (const float*)d_in[6];
    const float* t1b = (const float*)d_in[7];
    const float* T2  = (const float*)d_in[8];
    const float* t2b = (const float*)d_in[9];
    float* out = (float*)d_out;

    const int n = in_sizes[0] / INCH;       // 100000
    const int e = in_sizes[1] / 2;          // 3200000
    const int* row = ei;
    const int* col = ei + e;
    const int NB = (n + 1023) / 1024;       // 98 scan blocks
    const int scap = e + 4 * n;             // sorted capacity (edges + pads)

    // workspace layout — data-indexed buffer (sorted) last
    char* ws = (char*)d_ws;
    int*   deg   = (int*)ws;                          ws += (size_t)n * 4;
    int*   offs  = (int*)ws;                          ws += (size_t)n * 4;
    int*   cur   = (int*)ws;                          ws += (size_t)n * 4;
    float* inv   = (float*)ws;                        ws += (size_t)n * 4;
    int*   btot  = (int*)ws;                          ws += 4096;
    float* xT1   = (float*)ws;                        ws += (size_t)n * C1 * 4;
    float* h     = (float*)ws;                        ws += (size_t)n * C1 * 4;
    unsigned short* xW1s_bf = (unsigned short*)ws;    ws += (size_t)n * C1 * 2 + 64; // +zero row n
    unsigned short* hs_bf   = (unsigned short*)ws;    ws += (size_t)n * C1 * 2 + 64; // +zero row n
    int*   sorted= (int*)ws;                          ws += (size_t)scap * 4;        // 14.4 MB

    const int B = 256;

    init_kernel   <<<(n + B - 1) / B, B, 0, stream>>>(deg, n,
                    (int*)(xW1s_bf + (size_t)n * C1), (int*)(hs_bf + (size_t)n * C1));
    deg_kernel    <<<768, B, 0, stream>>>(row, col, deg, e, n);
    scan1_kernel  <<<NB, 1024, 0, stream>>>(deg, offs, btot, n);
    scan2_kernel  <<<1, 64, 0, stream>>>(btot, NB);
    scan3_kernel  <<<NB, 1024, 0, stream>>>(deg, offs, cur, inv, sorted, btot, n);
    scatter_kernel<<<768, B, 0, stream>>>(row, col, cur, sorted, e, n, scap);

    linear1_kernel <<<(n + 15) / 16, B, 0, stream>>>(x, W1, T1, t1b, inv, xW1s_bf, xT1, n);
    agg1_csr_kernel<<<(n + 63) / 64, B, 0, stream>>>(sorted, offs, deg, inv, xW1s_bf, xT1, b1, h, hs_bf, n);

    agg2_fused_kernel<<<(n + 63) / 64, B, 0, stream>>>(sorted, offs, deg, inv, hs_bf, h,
                                                       W2, T2, b2, t2b, out, n);
}

// Round 6
// 263.083 us; speedup vs baseline: 2.2720x; 2.2720x over previous
//
#include <hip/hip_runtime.h>

#define INCH 128
#define C1   16
#define C2   64
#define LOCB 7                   // log2(nodes per bucket)
#define BNODES (1 << LOCB)       // 128 nodes per bucket
#define CAP  8192                // padded edge capacity per bucket
#define ROWBITS 17
#define ROWMASK ((1 << ROWBITS) - 1)
#define SENT 0xFFFFFFFFu         // sentinel: src field = 0x1FFFF >= n -> filtered
#define ACCP 17                  // LDS acc row stride (odd -> 17*loc bijective mod 32)
#define FXS   524288.0f          // 2^19 fixed-point scale (folded into bf16 staging)
#define INVFX 1.9073486328125e-06f  // 2^-19

typedef int iv4 __attribute__((ext_vector_type(4)));
typedef unsigned short usv8 __attribute__((ext_vector_type(8)));

// bf16 helpers: RTNE store, shift load
__device__ __forceinline__ unsigned short f2bf(float f) {
    unsigned u = __float_as_uint(f);
    return (unsigned short)((u + 0x7FFF + ((u >> 16) & 1)) >> 16);
}
__device__ __forceinline__ float bf2f(unsigned short s) {
    return __uint_as_float((unsigned)s << 16);
}

// ---------------- binit: gcur[b] = b*CAP -----------------------------------
__global__ void binit_kernel(int* __restrict__ gcur, int K) {
    int t = blockIdx.x * blockDim.x + threadIdx.x;
    if (t < K) gcur[t] = t * CAP;
}

// ---------------- bucket edges, line-aligned padded reservations -----------
// (round-2/4 verified version: count -> 16-aligned reservation -> scatter via
//  LDS cursor -> sentinel pad. Write amplification accepted; staged write-out
//  (r3) and global CSR scatter (r5) both lost.)
__global__ __launch_bounds__(256) void bucket_kernel(
    const int* __restrict__ row, const int* __restrict__ col,
    int* __restrict__ gcur, int* __restrict__ barr,
    int e, int n, int K, int nblocks)
{
    __shared__ int cnt[1024];     // valid count per bucket
    __shared__ int cur[1024];     // write cursor
    __shared__ int sst[1024];     // chunk start
    int e4 = e >> 2;
    long b0 = (long)blockIdx.x * e4 / nblocks;
    long b1 = (long)(blockIdx.x + 1) * e4 / nblocks;
    const iv4* c4p = (const iv4*)col;
    const iv4* r4p = (const iv4*)row;
    for (int i = threadIdx.x; i < 1024; i += 256) cnt[i] = 0;
    __syncthreads();
    for (long i = b0 + threadIdx.x; i < b1; i += 256) {
        iv4 c4 = c4p[i], r4 = r4p[i];
        #pragma unroll
        for (int k = 0; k < 4; ++k) {
            unsigned c = (unsigned)c4[k], r = (unsigned)r4[k];
            if (c < (unsigned)n && r < (unsigned)n)
                atomicAdd(&cnt[c >> LOCB], 1);
        }
    }
    if (blockIdx.x == 0) {
        for (int i = e4 * 4 + threadIdx.x; i < e; i += 256) {
            unsigned c = (unsigned)col[i], r = (unsigned)row[i];
            if (c < (unsigned)n && r < (unsigned)n)
                atomicAdd(&cnt[c >> LOCB], 1);
        }
    }
    __syncthreads();
    for (int i = threadIdx.x; i < K; i += 256) {
        int c = cnt[i];
        int start = c ? atomicAdd(&gcur[i], (c + 15) & ~15) : 0;
        cur[i] = start;
        sst[i] = start;
    }
    __syncthreads();
    for (long i = b0 + threadIdx.x; i < b1; i += 256) {
        iv4 c4 = c4p[i], r4 = r4p[i];
        #pragma unroll
        for (int k = 0; k < 4; ++k) {
            unsigned c = (unsigned)c4[k], r = (unsigned)r4[k];
            if (c < (unsigned)n && r < (unsigned)n) {
                int b = c >> LOCB;
                int slot = atomicAdd(&cur[b], 1);          // LDS int atomic
                if ((unsigned)slot < (unsigned)((b + 1) * CAP))
                    barr[slot] = (int)(r | ((c & (BNODES - 1)) << ROWBITS));
            }
        }
    }
    if (blockIdx.x == 0) {
        for (int i = e4 * 4 + threadIdx.x; i < e; i += 256) {
            unsigned c = (unsigned)col[i], r = (unsigned)row[i];
            if (c < (unsigned)n && r < (unsigned)n) {
                int b = c >> LOCB;
                int slot = atomicAdd(&cur[b], 1);
                if ((unsigned)slot < (unsigned)((b + 1) * CAP))
                    barr[slot] = (int)(r | ((c & (BNODES - 1)) << ROWBITS));
            }
        }
    }
    __syncthreads();
    // sentinel-fill the pad so every reserved line is fully written
    for (int i = threadIdx.x; i < K; i += 256) {
        int c = cnt[i];
        if (!c) continue;
        int start = sst[i];
        int end = start + c;
        int re  = start + ((c + 15) & ~15);
        int lim = (i + 1) * CAP;
        if (end > lim) end = lim;
        if (re  > lim) re  = lim;
        for (int j = end; j < re; ++j) barr[j] = (int)SENT;
    }
}

// ---------------- degree/inv: per-bucket LDS histogram ---------------------
__global__ __launch_bounds__(256) void degree_kernel(
    const int* __restrict__ barr, const int* __restrict__ gcur,
    float* __restrict__ inv, int n)
{
    __shared__ int lcnt[BNODES];
    int b = blockIdx.x, tid = threadIdx.x;
    if (tid < BNODES) lcnt[tid] = 0;
    __syncthreads();
    int base = b * CAP;
    int len = gcur[b] - base;
    if (len < 0) len = 0;
    if (len > CAP) len = CAP;
    int len4 = len >> 2;
    const iv4* b4 = (const iv4*)(barr + base);
    for (int i = tid; i < len4; i += 256) {
        iv4 p4 = b4[i];
        #pragma unroll
        for (int k = 0; k < 4; ++k) {
            unsigned pk = (unsigned)p4[k];
            if ((pk & ROWMASK) < (unsigned)n)
                atomicAdd(&lcnt[(pk >> ROWBITS) & (BNODES - 1)], 1);
        }
    }
    __syncthreads();
    if (tid < BNODES) {
        int node = (b << LOCB) + tid;
        if (node < n) inv[node] = rsqrtf((float)lcnt[tid] + 1.0f);
    }
}

// ---------------- linear1: xW1s_bf = bf16((x@W1)*inv*2^19), xT1 ------------
__global__ __launch_bounds__(256) void linear1_kernel(
    const float* __restrict__ x, const float* __restrict__ W1,
    const float* __restrict__ T1, const float* __restrict__ t1b,
    const float* __restrict__ inv,
    unsigned short* __restrict__ xW1s_bf, float* __restrict__ xT1, int n)
{
    __shared__ float Wc[INCH][32];        // [:,0:16]=W1, [:,16:32]=t1_W
    __shared__ float xs[16][INCH + 4];
    int tid = threadIdx.x;

    for (int i = tid; i < INCH * C1; i += 256) {
        int k = i / C1, c = i % C1;
        Wc[k][c]      = W1[i];
        Wc[k][c + 16] = T1[i];
    }
    int node0 = blockIdx.x * 16;
    for (int i = tid; i < 16 * (INCH / 4); i += 256) {
        int r = i / (INCH / 4);
        int cc = i % (INCH / 4);
        int node = node0 + r;
        float4 v = make_float4(0.f, 0.f, 0.f, 0.f);
        if (node < n) v = ((const float4*)x)[(size_t)node * (INCH / 4) + cc];
        ((float4*)&xs[r][0])[cc] = v;
    }
    __syncthreads();

    int ch = tid & 15, nl = tid >> 4;
    int node = node0 + nl;
    if (node >= n) return;
    float a1 = 0.f, a2 = 0.f;
    #pragma unroll
    for (int k = 0; k < INCH; ++k) {
        float xv = xs[nl][k];
        a1 += xv * Wc[k][ch];
        a2 += xv * Wc[k][ch + 16];
    }
    // pre-scaled by inv[src] AND by 2^19 (exponent-only: exact in bf16)
    xW1s_bf[(node << 4) + ch] = f2bf(a1 * inv[node] * FXS);
    xT1[(node << 4) + ch]     = a2 + t1b[ch];
}

// ---- per-edge integer LDS accumulation: native ds_add_u32 (NOT float CAS) -
#define EDGE_ADDI(PK, V)                                                      \
    do {                                                                      \
        if (((PK) & ROWMASK) < un) {                                          \
            int* _a = &acc[(((PK) >> ROWBITS) & (BNODES - 1))][chb];          \
            _Pragma("unroll")                                                 \
            for (int _j = 0; _j < 8; ++_j)                                    \
                atomicAdd(&_a[_j], (int)rintf(bf2f((V)[_j])));                \
        }                                                                     \
    } while (0)

// ---- gather+scatter core: 2 lanes/edge-quad-half; lane loads 4 consecutive
//      barr words (dwordx4), 4 ushort8 gathers, 32 native ds_adds.
//      len is always a multiple of 16 -> strided 4-blocks cover exactly.
#define GATHER_SCATTER(SRCBUF)                                                \
    {                                                                         \
        int jj = tid >> 1;                                                    \
        for (int i0 = jj * 4; i0 + 3 < len; i0 += 512) {                      \
            iv4 w = *(const iv4*)(bp + i0);                                   \
            unsigned s0 = (unsigned)w[0] & ROWMASK, s1 = (unsigned)w[1] & ROWMASK; \
            unsigned s2 = (unsigned)w[2] & ROWMASK, s3 = (unsigned)w[3] & ROWMASK; \
            unsigned c0 = s0 < un ? s0 : 0u, c1 = s1 < un ? s1 : 0u;          \
            unsigned c2 = s2 < un ? s2 : 0u, c3 = s3 < un ? s3 : 0u;          \
            usv8 v0 = *(const usv8*)(SRCBUF + ((size_t)c0 << 4) + chb);       \
            usv8 v1 = *(const usv8*)(SRCBUF + ((size_t)c1 << 4) + chb);       \
            usv8 v2 = *(const usv8*)(SRCBUF + ((size_t)c2 << 4) + chb);       \
            usv8 v3 = *(const usv8*)(SRCBUF + ((size_t)c3 << 4) + chb);       \
            EDGE_ADDI((unsigned)w[0], v0);                                    \
            EDGE_ADDI((unsigned)w[1], v1);                                    \
            EDGE_ADDI((unsigned)w[2], v2);                                    \
            EDGE_ADDI((unsigned)w[3], v3);                                    \
        }                                                                     \
    }

// ---------------- agg1: bucket int-LDS accumulate + fused epilogue1 --------
__global__ __launch_bounds__(256) void agg1_bucket_kernel(
    const int* __restrict__ barr, const int* __restrict__ gcur,
    const float* __restrict__ inv, const unsigned short* __restrict__ xW1s_bf,
    const float* __restrict__ xT1, const float* __restrict__ b1,
    float* __restrict__ h, unsigned short* __restrict__ hs_bf, int n)
{
    __shared__ int acc[BNODES][ACCP];      // 8704 B, fixed-point 2^-19
    int b = blockIdx.x, tid = threadIdx.x;
    for (int i = tid; i < BNODES * ACCP; i += 256) (&acc[0][0])[i] = 0;
    __syncthreads();

    int base = b * CAP;
    int len = gcur[b] - base;
    if (len < 0) len = 0;
    if (len > CAP) len = CAP;
    const int* bp = barr + base;
    unsigned un = (unsigned)n;
    int chb = (tid & 1) << 3;              // channel half: 0..7 / 8..15

    GATHER_SCATTER(xW1s_bf)
    __syncthreads();

    // epilogue: self term (same 2^19 scale), unscale, bias, relu, +identity1
    for (int t = tid; t < BNODES * C1; t += 256) {
        int loc = t >> 4, ch = t & 15;
        int node = (b << LOCB) + loc;
        if (node >= n) continue;
        int idx = (node << 4) + ch;
        float ic = inv[node];
        float v = ((float)acc[loc][ch] + bf2f(xW1s_bf[idx])) * INVFX * ic + b1[ch];
        float hv = fmaxf(v, 0.f) + xT1[idx];
        h[idx]     = hv;
        hs_bf[idx] = f2bf(hv * ic * FXS);  // pre-scaled for layer-2 accumulation
    }
}

// ---------------- agg2: bucket int-LDS accumulate + fused 16->64 linears ---
__global__ __launch_bounds__(256) void agg2_bucket_kernel(
    const int* __restrict__ barr, const int* __restrict__ gcur,
    const float* __restrict__ inv, const unsigned short* __restrict__ hs_bf,
    const float* __restrict__ h,
    const float* __restrict__ W2, const float* __restrict__ T2,
    const float* __restrict__ b2, const float* __restrict__ t2b,
    float* __restrict__ out, int n)
{
    __shared__ int   acc[BNODES][ACCP];    // 8704 B (int in, float out in-place)
    __shared__ float Wc[C1][128];          // 8 KB: [:,0:64]=W2, [:,64:128]=T2
    __shared__ float h_s[BNODES][C1];      // 8 KB: unscaled h for identity2
    float* accf = (float*)&acc[0][0];      // same slots, stride ACCP
    int b = blockIdx.x, tid = threadIdx.x;
    for (int i = tid; i < BNODES * ACCP; i += 256) (&acc[0][0])[i] = 0;
    for (int i = tid; i < C1 * 128; i += 256) {
        int k = i >> 7, c = i & 127;
        Wc[k][c] = (c < 64) ? W2[k * C2 + c] : T2[k * C2 + (c - 64)];
    }
    {   // stage h rows (contiguous across bucket -> coalesced float4)
        int node0 = b << LOCB;
        for (int t = tid; t < BNODES * C1 / 4; t += 256) {
            float4 v = make_float4(0.f, 0.f, 0.f, 0.f);
            if (node0 + (t >> 2) < n) v = ((const float4*)h)[(size_t)node0 * 4 + t];
            ((float4*)&h_s[0][0])[t] = v;
        }
    }
    __syncthreads();

    int base = b * CAP;
    int len = gcur[b] - base;
    if (len < 0) len = 0;
    if (len > CAP) len = CAP;
    const int* bp = barr + base;
    unsigned un = (unsigned)n;
    int chb = (tid & 1) << 3;

    GATHER_SCATTER(hs_bf)
    __syncthreads();

    // finalize: add self (same scale), unscale, *inv -> float, in place
    for (int t = tid; t < BNODES * C1; t += 256) {
        int loc = t >> 4, ch = t & 15;
        int node = (b << LOCB) + loc;
        float v = 0.f;
        if (node < n)
            v = ((float)acc[loc][ch] + bf2f(hs_bf[(node << 4) + ch])) * INVFX * inv[node];
        accf[loc * ACCP + ch] = v;
    }
    __syncthreads();

    // 16->64 matmuls: weights hoisted to registers, acc/h_s broadcast reads
    int och = tid & 63, g = tid >> 6;      // wave g handles locs [32g, 32g+32)
    float w1r[C1], w2r[C1];
    #pragma unroll
    for (int k = 0; k < C1; ++k) { w1r[k] = Wc[k][och]; w2r[k] = Wc[k][och + 64]; }
    float bb = b2[och], tb = t2b[och];
    for (int q = 0; q < 32; ++q) {
        int loc = (g << 5) + q;
        int node2 = (b << LOCB) + loc;
        if (node2 >= n) continue;
        float s1 = bb, s2 = tb;
        #pragma unroll
        for (int k = 0; k < C1; ++k) {
            s1 += accf[loc * ACCP + k] * w1r[k];
            s2 += h_s[loc][k]          * w2r[k];
        }
        out[(size_t)node2 * C2 + och] = fmaxf(s1, 0.f) + s2;
    }
}

extern "C" void kernel_launch(void* const* d_in, const int* in_sizes, int n_in,
                              void* d_out, int out_size, void* d_ws, size_t ws_size,
                              hipStream_t stream) {
    const float* x   = (const float*)d_in[0];
    const int*   ei  = (const int*)d_in[1];
    const float* W1  = (const float*)d_in[2];
    const float* b1  = (const float*)d_in[3];
    const float* W2  = (const float*)d_in[4];
    const float* b2  = (const float*)d_in[5];
    const float* T1  = (const float*)d_in[6];
    const float* t1b = (const float*)d_in[7];
    const float* T2  = (const float*)d_in[8];
    const float* t2b = (const float*)d_in[9];
    float* out = (float*)d_out;

    const int n = in_sizes[0] / INCH;       // 100000
    const int e = in_sizes[1] / 2;          // 3200000
    const int* row = ei;
    const int* col = ei + e;
    const int K = (n + BNODES - 1) >> LOCB; // 782 buckets

    // workspace layout (sorted/offs/cnt/bbase dropped: -40 MB)
    char* ws = (char*)d_ws;
    int*   gcur  = (int*)ws;                          ws += 4096;
    float* inv   = (float*)ws;                        ws += (size_t)n * 4;
    float* xT1   = (float*)ws;                        ws += (size_t)n * C1 * 4;
    float* h     = (float*)ws;                        ws += (size_t)n * C1 * 4;
    unsigned short* xW1s_bf = (unsigned short*)ws;    ws += (size_t)n * C1 * 2;
    unsigned short* hs_bf   = (unsigned short*)ws;    ws += (size_t)n * C1 * 2;
    int*   barr  = (int*)ws;                          ws += (size_t)K * CAP * 4; // 25.6 MB

    const int B = 256;
    const int nbb = 390;     // bucket_kernel blocks

    binit_kernel  <<<(K + B - 1) / B, B, 0, stream>>>(gcur, K);
    bucket_kernel <<<nbb, B, 0, stream>>>(row, col, gcur, barr, e, n, K, nbb);
    degree_kernel <<<K, B, 0, stream>>>(barr, gcur, inv, n);

    linear1_kernel <<<(n + 15) / 16, B, 0, stream>>>(x, W1, T1, t1b, inv, xW1s_bf, xT1, n);
    agg1_bucket_kernel<<<K, B, 0, stream>>>(barr, gcur, inv, xW1s_bf, xT1, b1, h, hs_bf, n);
    agg2_bucket_kernel<<<K, B, 0, stream>>>(barr, gcur, inv, hs_bf, h,
                                            W2, T2, b2, t2b, out, n);
}

// Round 7
// 251.771 us; speedup vs baseline: 2.3740x; 1.0449x over previous
//
#include <hip/hip_runtime.h>

#define INCH 128
#define C1   16
#define C2   64
#define LOCB 7                   // log2(nodes per bucket)
#define BNODES (1 << LOCB)       // 128 nodes per bucket
#define CAP  8192                // padded edge capacity per bucket
#define ROWBITS 17
#define ROWMASK ((1 << ROWBITS) - 1)
#define SENT 0xFFFFFFFFu         // sentinel: src field = 0x1FFFF >= n -> filtered
#define ACCP 17                  // LDS acc row stride (odd -> 17*loc bijective mod 32)
#define FXS   524288.0f          // 2^19 fixed-point scale (folded into bf16 staging)
#define INVFX 1.9073486328125e-06f  // 2^-19
#define BKT_T 1024               // bucket_kernel threads (occupancy: 6->24 waves/CU)
#define AGG_T 512                // agg/degree threads   (occupancy: 12->24 waves/CU)

typedef int iv4 __attribute__((ext_vector_type(4)));
typedef unsigned short usv8 __attribute__((ext_vector_type(8)));

// bf16 helpers: RTNE store, shift load
__device__ __forceinline__ unsigned short f2bf(float f) {
    unsigned u = __float_as_uint(f);
    return (unsigned short)((u + 0x7FFF + ((u >> 16) & 1)) >> 16);
}
__device__ __forceinline__ float bf2f(unsigned short s) {
    return __uint_as_float((unsigned)s << 16);
}

// ---------------- binit: gcur[b] = b*CAP -----------------------------------
__global__ void binit_kernel(int* __restrict__ gcur, int K) {
    int t = blockIdx.x * blockDim.x + threadIdx.x;
    if (t < K) gcur[t] = t * CAP;
}

// ---------------- bucket edges, line-aligned padded reservations -----------
// Verified structure (r2/r4); r7: 1024 threads for latency hiding.
__global__ __launch_bounds__(BKT_T) void bucket_kernel(
    const int* __restrict__ row, const int* __restrict__ col,
    int* __restrict__ gcur, int* __restrict__ barr,
    int e, int n, int K, int nblocks)
{
    __shared__ int cnt[1024];     // valid count per bucket
    __shared__ int cur[1024];     // write cursor
    __shared__ int sst[1024];     // chunk start
    int tid = threadIdx.x;
    int e4 = e >> 2;
    long b0 = (long)blockIdx.x * e4 / nblocks;
    long b1 = (long)(blockIdx.x + 1) * e4 / nblocks;
    const iv4* c4p = (const iv4*)col;
    const iv4* r4p = (const iv4*)row;
    cnt[tid] = 0;
    __syncthreads();
    for (long i = b0 + tid; i < b1; i += BKT_T) {
        iv4 c4 = c4p[i], r4 = r4p[i];
        #pragma unroll
        for (int k = 0; k < 4; ++k) {
            unsigned c = (unsigned)c4[k], r = (unsigned)r4[k];
            if (c < (unsigned)n && r < (unsigned)n)
                atomicAdd(&cnt[c >> LOCB], 1);
        }
    }
    if (blockIdx.x == 0) {
        for (int i = e4 * 4 + tid; i < e; i += BKT_T) {
            unsigned c = (unsigned)col[i], r = (unsigned)row[i];
            if (c < (unsigned)n && r < (unsigned)n)
                atomicAdd(&cnt[c >> LOCB], 1);
        }
    }
    __syncthreads();
    if (tid < K) {
        int c = cnt[tid];
        int start = c ? atomicAdd(&gcur[tid], (c + 15) & ~15) : 0;
        cur[tid] = start;
        sst[tid] = start;
    }
    __syncthreads();
    for (long i = b0 + tid; i < b1; i += BKT_T) {
        iv4 c4 = c4p[i], r4 = r4p[i];
        #pragma unroll
        for (int k = 0; k < 4; ++k) {
            unsigned c = (unsigned)c4[k], r = (unsigned)r4[k];
            if (c < (unsigned)n && r < (unsigned)n) {
                int b = c >> LOCB;
                int slot = atomicAdd(&cur[b], 1);          // LDS int atomic
                if ((unsigned)slot < (unsigned)((b + 1) * CAP))
                    barr[slot] = (int)(r | ((c & (BNODES - 1)) << ROWBITS));
            }
        }
    }
    if (blockIdx.x == 0) {
        for (int i = e4 * 4 + tid; i < e; i += BKT_T) {
            unsigned c = (unsigned)col[i], r = (unsigned)row[i];
            if (c < (unsigned)n && r < (unsigned)n) {
                int b = c >> LOCB;
                int slot = atomicAdd(&cur[b], 1);
                if ((unsigned)slot < (unsigned)((b + 1) * CAP))
                    barr[slot] = (int)(r | ((c & (BNODES - 1)) << ROWBITS));
            }
        }
    }
    __syncthreads();
    // sentinel-fill the pad so every reserved line is fully written
    if (tid < K) {
        int c = cnt[tid];
        if (c) {
            int start = sst[tid];
            int end = start + c;
            int re  = start + ((c + 15) & ~15);
            int lim = (tid + 1) * CAP;
            if (end > lim) end = lim;
            if (re  > lim) re  = lim;
            for (int j = end; j < re; ++j) barr[j] = (int)SENT;
        }
    }
}

// ---------------- degree/inv: per-bucket LDS histogram ---------------------
__global__ __launch_bounds__(AGG_T) void degree_kernel(
    const int* __restrict__ barr, const int* __restrict__ gcur,
    float* __restrict__ inv, int n)
{
    __shared__ int lcnt[BNODES];
    int b = blockIdx.x, tid = threadIdx.x;
    if (tid < BNODES) lcnt[tid] = 0;
    __syncthreads();
    int base = b * CAP;
    int len = gcur[b] - base;
    if (len < 0) len = 0;
    if (len > CAP) len = CAP;
    int len4 = len >> 2;
    const iv4* b4 = (const iv4*)(barr + base);
    for (int i = tid; i < len4; i += AGG_T) {
        iv4 p4 = b4[i];
        #pragma unroll
        for (int k = 0; k < 4; ++k) {
            unsigned pk = (unsigned)p4[k];
            if ((pk & ROWMASK) < (unsigned)n)
                atomicAdd(&lcnt[(pk >> ROWBITS) & (BNODES - 1)], 1);
        }
    }
    __syncthreads();
    if (tid < BNODES) {
        int node = (b << LOCB) + tid;
        if (node < n) inv[node] = rsqrtf((float)lcnt[tid] + 1.0f);
    }
}

// ---------------- linear1: xW1s_bf = bf16((x@W1)*inv*2^19), xT1 ------------
__global__ __launch_bounds__(256) void linear1_kernel(
    const float* __restrict__ x, const float* __restrict__ W1,
    const float* __restrict__ T1, const float* __restrict__ t1b,
    const float* __restrict__ inv,
    unsigned short* __restrict__ xW1s_bf, float* __restrict__ xT1, int n)
{
    __shared__ float Wc[INCH][32];        // [:,0:16]=W1, [:,16:32]=t1_W
    __shared__ float xs[16][INCH + 4];
    int tid = threadIdx.x;

    for (int i = tid; i < INCH * C1; i += 256) {
        int k = i / C1, c = i % C1;
        Wc[k][c]      = W1[i];
        Wc[k][c + 16] = T1[i];
    }
    int node0 = blockIdx.x * 16;
    for (int i = tid; i < 16 * (INCH / 4); i += 256) {
        int r = i / (INCH / 4);
        int cc = i % (INCH / 4);
        int node = node0 + r;
        float4 v = make_float4(0.f, 0.f, 0.f, 0.f);
        if (node < n) v = ((const float4*)x)[(size_t)node * (INCH / 4) + cc];
        ((float4*)&xs[r][0])[cc] = v;
    }
    __syncthreads();

    int ch = tid & 15, nl = tid >> 4;
    int node = node0 + nl;
    if (node >= n) return;
    float a1 = 0.f, a2 = 0.f;
    #pragma unroll
    for (int k = 0; k < INCH; ++k) {
        float xv = xs[nl][k];
        a1 += xv * Wc[k][ch];
        a2 += xv * Wc[k][ch + 16];
    }
    // pre-scaled by inv[src] AND by 2^19 (exponent-only: exact in bf16)
    xW1s_bf[(node << 4) + ch] = f2bf(a1 * inv[node] * FXS);
    xT1[(node << 4) + ch]     = a2 + t1b[ch];
}

// ---- per-edge integer LDS accumulation: native ds_add_u32 (NOT float CAS) -
#define EDGE_ADDI(PK, V)                                                      \
    do {                                                                      \
        if (((PK) & ROWMASK) < un) {                                          \
            int* _a = &acc[(((PK) >> ROWBITS) & (BNODES - 1))][chb];          \
            _Pragma("unroll")                                                 \
            for (int _j = 0; _j < 8; ++_j)                                    \
                atomicAdd(&_a[_j], (int)rintf(bf2f((V)[_j])));                \
        }                                                                     \
    } while (0)

// ---- gather+scatter core: 2 lanes/edge-quad-half; lane loads 4 consecutive
//      barr words (dwordx4), 4 ushort8 gathers, 32 native ds_adds.
//      len is always a multiple of 16 -> strided 4-blocks cover exactly.
#define GATHER_SCATTER(SRCBUF)                                                \
    {                                                                         \
        int jj = tid >> 1;                                                    \
        for (int i0 = jj * 4; i0 + 3 < len; i0 += (AGG_T * 2)) {              \
            iv4 w = *(const iv4*)(bp + i0);                                   \
            unsigned s0 = (unsigned)w[0] & ROWMASK, s1 = (unsigned)w[1] & ROWMASK; \
            unsigned s2 = (unsigned)w[2] & ROWMASK, s3 = (unsigned)w[3] & ROWMASK; \
            unsigned c0 = s0 < un ? s0 : 0u, c1 = s1 < un ? s1 : 0u;          \
            unsigned c2 = s2 < un ? s2 : 0u, c3 = s3 < un ? s3 : 0u;          \
            usv8 v0 = *(const usv8*)(SRCBUF + ((size_t)c0 << 4) + chb);       \
            usv8 v1 = *(const usv8*)(SRCBUF + ((size_t)c1 << 4) + chb);       \
            usv8 v2 = *(const usv8*)(SRCBUF + ((size_t)c2 << 4) + chb);       \
            usv8 v3 = *(const usv8*)(SRCBUF + ((size_t)c3 << 4) + chb);       \
            EDGE_ADDI((unsigned)w[0], v0);                                    \
            EDGE_ADDI((unsigned)w[1], v1);                                    \
            EDGE_ADDI((unsigned)w[2], v2);                                    \
            EDGE_ADDI((unsigned)w[3], v3);                                    \
        }                                                                     \
    }

// ---------------- agg1: bucket int-LDS accumulate + fused epilogue1 --------
__global__ __launch_bounds__(AGG_T) void agg1_bucket_kernel(
    const int* __restrict__ barr, const int* __restrict__ gcur,
    const float* __restrict__ inv, const unsigned short* __restrict__ xW1s_bf,
    const float* __restrict__ xT1, const float* __restrict__ b1,
    float* __restrict__ h, unsigned short* __restrict__ hs_bf, int n)
{
    __shared__ int acc[BNODES][ACCP];      // 8704 B, fixed-point 2^-19
    int b = blockIdx.x, tid = threadIdx.x;
    for (int i = tid; i < BNODES * ACCP; i += AGG_T) (&acc[0][0])[i] = 0;
    __syncthreads();

    int base = b * CAP;
    int len = gcur[b] - base;
    if (len < 0) len = 0;
    if (len > CAP) len = CAP;
    const int* bp = barr + base;
    unsigned un = (unsigned)n;
    int chb = (tid & 1) << 3;              // channel half: 0..7 / 8..15

    GATHER_SCATTER(xW1s_bf)
    __syncthreads();

    // epilogue: self term (same 2^19 scale), unscale, bias, relu, +identity1
    for (int t = tid; t < BNODES * C1; t += AGG_T) {
        int loc = t >> 4, ch = t & 15;
        int node = (b << LOCB) + loc;
        if (node >= n) continue;
        int idx = (node << 4) + ch;
        float ic = inv[node];
        float v = ((float)acc[loc][ch] + bf2f(xW1s_bf[idx])) * INVFX * ic + b1[ch];
        float hv = fmaxf(v, 0.f) + xT1[idx];
        h[idx]     = hv;
        hs_bf[idx] = f2bf(hv * ic * FXS);  // pre-scaled for layer-2 accumulation
    }
}

// ---------------- agg2: bucket int-LDS accumulate + fused 16->64 linears ---
__global__ __launch_bounds__(AGG_T) void agg2_bucket_kernel(
    const int* __restrict__ barr, const int* __restrict__ gcur,
    const float* __restrict__ inv, const unsigned short* __restrict__ hs_bf,
    const float* __restrict__ h,
    const float* __restrict__ W2, const float* __restrict__ T2,
    const float* __restrict__ b2, const float* __restrict__ t2b,
    float* __restrict__ out, int n)
{
    __shared__ int   acc[BNODES][ACCP];    // 8704 B (int in, float out in-place)
    __shared__ float Wc[C1][128];          // 8 KB: [:,0:64]=W2, [:,64:128]=T2
    __shared__ float h_s[BNODES][C1];      // 8 KB: unscaled h for identity2
    float* accf = (float*)&acc[0][0];      // same slots, stride ACCP
    int b = blockIdx.x, tid = threadIdx.x;
    for (int i = tid; i < BNODES * ACCP; i += AGG_T) (&acc[0][0])[i] = 0;
    for (int i = tid; i < C1 * 128; i += AGG_T) {
        int k = i >> 7, c = i & 127;
        Wc[k][c] = (c < 64) ? W2[k * C2 + c] : T2[k * C2 + (c - 64)];
    }
    {   // stage h rows (contiguous across bucket -> coalesced float4)
        int node0 = b << LOCB;
        for (int t = tid; t < BNODES * C1 / 4; t += AGG_T) {
            float4 v = make_float4(0.f, 0.f, 0.f, 0.f);
            if (node0 + (t >> 2) < n) v = ((const float4*)h)[(size_t)node0 * 4 + t];
            ((float4*)&h_s[0][0])[t] = v;
        }
    }
    __syncthreads();

    int base = b * CAP;
    int len = gcur[b] - base;
    if (len < 0) len = 0;
    if (len > CAP) len = CAP;
    const int* bp = barr + base;
    unsigned un = (unsigned)n;
    int chb = (tid & 1) << 3;

    GATHER_SCATTER(hs_bf)
    __syncthreads();

    // finalize: add self (same scale), unscale, *inv -> float, in place
    for (int t = tid; t < BNODES * C1; t += AGG_T) {
        int loc = t >> 4, ch = t & 15;
        int node = (b << LOCB) + loc;
        float v = 0.f;
        if (node < n)
            v = ((float)acc[loc][ch] + bf2f(hs_bf[(node << 4) + ch])) * INVFX * inv[node];
        accf[loc * ACCP + ch] = v;
    }
    __syncthreads();

    // 16->64 matmuls: weights hoisted to registers, acc/h_s broadcast reads
    int och = tid & 63, g = tid >> 6;      // 8 groups x 16 locs
    float w1r[C1], w2r[C1];
    #pragma unroll
    for (int k = 0; k < C1; ++k) { w1r[k] = Wc[k][och]; w2r[k] = Wc[k][och + 64]; }
    float bb = b2[och], tb = t2b[och];
    for (int q = 0; q < 16; ++q) {
        int loc = (g << 4) + q;
        int node2 = (b << LOCB) + loc;
        if (node2 >= n) continue;
        float s1 = bb, s2 = tb;
        #pragma unroll
        for (int k = 0; k < C1; ++k) {
            s1 += accf[loc * ACCP + k] * w1r[k];
            s2 += h_s[loc][k]          * w2r[k];
        }
        out[(size_t)node2 * C2 + och] = fmaxf(s1, 0.f) + s2;
    }
}

extern "C" void kernel_launch(void* const* d_in, const int* in_sizes, int n_in,
                              void* d_out, int out_size, void* d_ws, size_t ws_size,
                              hipStream_t stream) {
    const float* x   = (const float*)d_in[0];
    const int*   ei  = (const int*)d_in[1];
    const float* W1  = (const float*)d_in[2];
    const float* b1  = (const float*)d_in[3];
    const float* W2  = (const float*)d_in[4];
    const float* b2  = (const float*)d_in[5];
    const float* T1  = (const float*)d_in[6];
    const float* t1b = (const float*)d_in[7];
    const float* T2  = (const float*)d_in[8];
    const float* t2b = (const float*)d_in[9];
    float* out = (float*)d_out;

    const int n = in_sizes[0] / INCH;       // 100000
    const int e = in_sizes[1] / 2;          // 3200000
    const int* row = ei;
    const int* col = ei + e;
    const int K = (n + BNODES - 1) >> LOCB; // 782 buckets

    // workspace layout
    char* ws = (char*)d_ws;
    int*   gcur  = (int*)ws;                          ws += 4096;
    float* inv   = (float*)ws;                        ws += (size_t)n * 4;
    float* xT1   = (float*)ws;                        ws += (size_t)n * C1 * 4;
    float* h     = (float*)ws;                        ws += (size_t)n * C1 * 4;
    unsigned short* xW1s_bf = (unsigned short*)ws;    ws += (size_t)n * C1 * 2;
    unsigned short* hs_bf   = (unsigned short*)ws;    ws += (size_t)n * C1 * 2;
    int*   barr  = (int*)ws;                          ws += (size_t)K * CAP * 4; // 25.6 MB

    const int nbb = 390;     // bucket_kernel blocks

    binit_kernel  <<<(K + 255) / 256, 256, 0, stream>>>(gcur, K);
    bucket_kernel <<<nbb, BKT_T, 0, stream>>>(row, col, gcur, barr, e, n, K, nbb);
    degree_kernel <<<K, AGG_T, 0, stream>>>(barr, gcur, inv, n);

    linear1_kernel <<<(n + 15) / 16, 256, 0, stream>>>(x, W1, T1, t1b, inv, xW1s_bf, xT1, n);
    agg1_bucket_kernel<<<K, AGG_T, 0, stream>>>(barr, gcur, inv, xW1s_bf, xT1, b1, h, hs_bf, n);
    agg2_bucket_kernel<<<K, AGG_T, 0, stream>>>(barr, gcur, inv, hs_bf, h,
                                                W2, T2, b2, t2b, out, n);
}

// Round 8
// 249.576 us; speedup vs baseline: 2.3949x; 1.0088x over previous
//
#include <hip/hip_runtime.h>

#define INCH 128
#define C1   16
#define C2   64
#define LOCB 7                   // log2(nodes per bucket)
#define BNODES (1 << LOCB)       // 128 nodes per bucket
#define CAP  8192                // padded edge capacity per bucket
#define ROWBITS 17
#define ROWMASK ((1 << ROWBITS) - 1)
#define SENT 0xFFFFFFFFu         // sentinel: src field = 0x1FFFF >= n -> filtered
#define ACC2P 9                  // u64 acc row stride (odd -> bank-pair spread)
#define FXS   16384.0f           // 2^14 fixed-point scale (folded into bf16 staging)
#define INVFX 6.103515625e-05f   // 2^-14
#define FXBH  524288.5f          // 2^19 bias + 0.5 (round-half-up via trunc)
#define BSH   19                 // bias shift for de-biasing
#define BKT_T 1024               // bucket_kernel threads
#define AGG_T 512                // agg/degree threads

typedef int iv4 __attribute__((ext_vector_type(4)));
typedef unsigned short usv8 __attribute__((ext_vector_type(8)));

// bf16 helpers: RTNE store, shift load
__device__ __forceinline__ unsigned short f2bf(float f) {
    unsigned u = __float_as_uint(f);
    return (unsigned short)((u + 0x7FFF + ((u >> 16) & 1)) >> 16);
}
__device__ __forceinline__ float bf2f(unsigned short s) {
    return __uint_as_float((unsigned)s << 16);
}

// ---------------- binit: gcur[b] = b*CAP -----------------------------------
__global__ void binit_kernel(int* __restrict__ gcur, int K) {
    int t = blockIdx.x * blockDim.x + threadIdx.x;
    if (t < K) gcur[t] = t * CAP;
}

// ---------------- bucket edges, line-aligned padded reservations -----------
// Verified structure (r2/r4); r7: 1024 threads for latency hiding.
__global__ __launch_bounds__(BKT_T) void bucket_kernel(
    const int* __restrict__ row, const int* __restrict__ col,
    int* __restrict__ gcur, int* __restrict__ barr,
    int e, int n, int K, int nblocks)
{
    __shared__ int cnt[1024];     // valid count per bucket
    __shared__ int cur[1024];     // write cursor
    __shared__ int sst[1024];     // chunk start
    int tid = threadIdx.x;
    int e4 = e >> 2;
    long b0 = (long)blockIdx.x * e4 / nblocks;
    long b1 = (long)(blockIdx.x + 1) * e4 / nblocks;
    const iv4* c4p = (const iv4*)col;
    const iv4* r4p = (const iv4*)row;
    cnt[tid] = 0;
    __syncthreads();
    for (long i = b0 + tid; i < b1; i += BKT_T) {
        iv4 c4 = c4p[i], r4 = r4p[i];
        #pragma unroll
        for (int k = 0; k < 4; ++k) {
            unsigned c = (unsigned)c4[k], r = (unsigned)r4[k];
            if (c < (unsigned)n && r < (unsigned)n)
                atomicAdd(&cnt[c >> LOCB], 1);
        }
    }
    if (blockIdx.x == 0) {
        for (int i = e4 * 4 + tid; i < e; i += BKT_T) {
            unsigned c = (unsigned)col[i], r = (unsigned)row[i];
            if (c < (unsigned)n && r < (unsigned)n)
                atomicAdd(&cnt[c >> LOCB], 1);
        }
    }
    __syncthreads();
    if (tid < K) {
        int c = cnt[tid];
        int start = c ? atomicAdd(&gcur[tid], (c + 15) & ~15) : 0;
        cur[tid] = start;
        sst[tid] = start;
    }
    __syncthreads();
    for (long i = b0 + tid; i < b1; i += BKT_T) {
        iv4 c4 = c4p[i], r4 = r4p[i];
        #pragma unroll
        for (int k = 0; k < 4; ++k) {
            unsigned c = (unsigned)c4[k], r = (unsigned)r4[k];
            if (c < (unsigned)n && r < (unsigned)n) {
                int b = c >> LOCB;
                int slot = atomicAdd(&cur[b], 1);          // LDS int atomic
                if ((unsigned)slot < (unsigned)((b + 1) * CAP))
                    barr[slot] = (int)(r | ((c & (BNODES - 1)) << ROWBITS));
            }
        }
    }
    if (blockIdx.x == 0) {
        for (int i = e4 * 4 + tid; i < e; i += BKT_T) {
            unsigned c = (unsigned)col[i], r = (unsigned)row[i];
            if (c < (unsigned)n && r < (unsigned)n) {
                int b = c >> LOCB;
                int slot = atomicAdd(&cur[b], 1);
                if ((unsigned)slot < (unsigned)((b + 1) * CAP))
                    barr[slot] = (int)(r | ((c & (BNODES - 1)) << ROWBITS));
            }
        }
    }
    __syncthreads();
    // sentinel-fill the pad so every reserved line is fully written
    if (tid < K) {
        int c = cnt[tid];
        if (c) {
            int start = sst[tid];
            int end = start + c;
            int re  = start + ((c + 15) & ~15);
            int lim = (tid + 1) * CAP;
            if (end > lim) end = lim;
            if (re  > lim) re  = lim;
            for (int j = end; j < re; ++j) barr[j] = (int)SENT;
        }
    }
}

// ---------------- degree/inv: per-bucket LDS histogram (now also deg[]) ----
__global__ __launch_bounds__(AGG_T) void degree_kernel(
    const int* __restrict__ barr, const int* __restrict__ gcur,
    float* __restrict__ inv, int* __restrict__ deg, int n)
{
    __shared__ int lcnt[BNODES];
    int b = blockIdx.x, tid = threadIdx.x;
    if (tid < BNODES) lcnt[tid] = 0;
    __syncthreads();
    int base = b * CAP;
    int len = gcur[b] - base;
    if (len < 0) len = 0;
    if (len > CAP) len = CAP;
    int len4 = len >> 2;
    const iv4* b4 = (const iv4*)(barr + base);
    for (int i = tid; i < len4; i += AGG_T) {
        iv4 p4 = b4[i];
        #pragma unroll
        for (int k = 0; k < 4; ++k) {
            unsigned pk = (unsigned)p4[k];
            if ((pk & ROWMASK) < (unsigned)n)
                atomicAdd(&lcnt[(pk >> ROWBITS) & (BNODES - 1)], 1);
        }
    }
    __syncthreads();
    if (tid < BNODES) {
        int node = (b << LOCB) + tid;
        if (node < n) {
            deg[node] = lcnt[tid];
            inv[node] = rsqrtf((float)lcnt[tid] + 1.0f);
        }
    }
}

// ---------------- linear1: xW1s_bf = bf16((x@W1)*inv*2^14), xT1 ------------
__global__ __launch_bounds__(256) void linear1_kernel(
    const float* __restrict__ x, const float* __restrict__ W1,
    const float* __restrict__ T1, const float* __restrict__ t1b,
    const float* __restrict__ inv,
    unsigned short* __restrict__ xW1s_bf, float* __restrict__ xT1, int n)
{
    __shared__ float Wc[INCH][32];        // [:,0:16]=W1, [:,16:32]=t1_W
    __shared__ float xs[16][INCH + 4];
    int tid = threadIdx.x;

    for (int i = tid; i < INCH * C1; i += 256) {
        int k = i / C1, c = i % C1;
        Wc[k][c]      = W1[i];
        Wc[k][c + 16] = T1[i];
    }
    int node0 = blockIdx.x * 16;
    for (int i = tid; i < 16 * (INCH / 4); i += 256) {
        int r = i / (INCH / 4);
        int cc = i % (INCH / 4);
        int node = node0 + r;
        float4 v = make_float4(0.f, 0.f, 0.f, 0.f);
        if (node < n) v = ((const float4*)x)[(size_t)node * (INCH / 4) + cc];
        ((float4*)&xs[r][0])[cc] = v;
    }
    __syncthreads();

    int ch = tid & 15, nl = tid >> 4;
    int node = node0 + nl;
    if (node >= n) return;
    float a1 = 0.f, a2 = 0.f;
    #pragma unroll
    for (int k = 0; k < INCH; ++k) {
        float xv = xs[nl][k];
        a1 += xv * Wc[k][ch];
        a2 += xv * Wc[k][ch + 16];
    }
    // pre-scaled by inv[src] AND by 2^14 (exponent-only: exact in bf16)
    xW1s_bf[(node << 4) + ch] = f2bf(a1 * inv[node] * FXS);
    xT1[(node << 4) + ch]     = a2 + t1b[ch];
}

// ---- per-edge packed 64-bit LDS accumulation: native ds_add_u64.
//      Two channels per word, each half biased by 2^19 (non-negative ->
//      no cross-half borrow); de-biased in epilogue via deg<<19.
#define EDGE_ADDI64(PK, V)                                                    \
    do {                                                                      \
        if (((PK) & ROWMASK) < un) {                                          \
            unsigned long long* _a = &acc[(((PK) >> ROWBITS) & (BNODES - 1))][tb]; \
            _Pragma("unroll")                                                 \
            for (int _j = 0; _j < 4; ++_j) {                                  \
                unsigned _lo = (unsigned)(bf2f((V)[2 * _j])     + FXBH);      \
                unsigned _hi = (unsigned)(bf2f((V)[2 * _j + 1]) + FXBH);      \
                atomicAdd(&_a[_j], ((unsigned long long)_hi << 32) | _lo);    \
            }                                                                 \
        }                                                                     \
    } while (0)

// ---- gather+scatter core: 2 lanes/edge-quad-half; lane loads 4 consecutive
//      barr words (dwordx4), 4 ushort8 gathers, 16 ds_add_u64 per 4 edges.
#define GATHER_SCATTER(SRCBUF)                                                \
    {                                                                         \
        int jj = tid >> 1;                                                    \
        for (int i0 = jj * 4; i0 + 3 < len; i0 += (AGG_T * 2)) {              \
            iv4 w = *(const iv4*)(bp + i0);                                   \
            unsigned s0 = (unsigned)w[0] & ROWMASK, s1 = (unsigned)w[1] & ROWMASK; \
            unsigned s2 = (unsigned)w[2] & ROWMASK, s3 = (unsigned)w[3] & ROWMASK; \
            unsigned c0 = s0 < un ? s0 : 0u, c1 = s1 < un ? s1 : 0u;          \
            unsigned c2 = s2 < un ? s2 : 0u, c3 = s3 < un ? s3 : 0u;          \
            usv8 v0 = *(const usv8*)(SRCBUF + ((size_t)c0 << 4) + chb);       \
            usv8 v1 = *(const usv8*)(SRCBUF + ((size_t)c1 << 4) + chb);       \
            usv8 v2 = *(const usv8*)(SRCBUF + ((size_t)c2 << 4) + chb);       \
            usv8 v3 = *(const usv8*)(SRCBUF + ((size_t)c3 << 4) + chb);       \
            EDGE_ADDI64((unsigned)w[0], v0);                                  \
            EDGE_ADDI64((unsigned)w[1], v1);                                  \
            EDGE_ADDI64((unsigned)w[2], v2);                                  \
            EDGE_ADDI64((unsigned)w[3], v3);                                  \
        }                                                                     \
    }

// ---------------- agg1: bucket u64-LDS accumulate + fused epilogue1 --------
__global__ __launch_bounds__(AGG_T) void agg1_bucket_kernel(
    const int* __restrict__ barr, const int* __restrict__ gcur,
    const float* __restrict__ inv, const int* __restrict__ deg,
    const unsigned short* __restrict__ xW1s_bf,
    const float* __restrict__ xT1, const float* __restrict__ b1,
    float* __restrict__ h, unsigned short* __restrict__ hs_bf, int n)
{
    __shared__ unsigned long long acc[BNODES][ACC2P];   // 9216 B
    int b = blockIdx.x, tid = threadIdx.x;
    for (int i = tid; i < BNODES * ACC2P; i += AGG_T) (&acc[0][0])[i] = 0ull;
    __syncthreads();

    int base = b * CAP;
    int len = gcur[b] - base;
    if (len < 0) len = 0;
    if (len > CAP) len = CAP;
    const int* bp = barr + base;
    unsigned un = (unsigned)n;
    int chb = (tid & 1) << 3;              // channel half: 0..7 / 8..15
    int tb  = (tid & 1) << 2;              // u64 slot base: 0..3 / 4..7

    GATHER_SCATTER(xW1s_bf)
    __syncthreads();

    // epilogue: de-bias, self term (same 2^14 scale), unscale, bias, relu
    for (int t = tid; t < BNODES * C1; t += AGG_T) {
        int loc = t >> 4, ch = t & 15;
        int node = (b << LOCB) + loc;
        if (node >= n) continue;
        int idx = (node << 4) + ch;
        unsigned long long w = acc[loc][ch >> 1];
        unsigned wd = (ch & 1) ? (unsigned)(w >> 32) : (unsigned)w;
        int sv = (int)(wd - ((unsigned)deg[node] << BSH));
        float ic = inv[node];
        float v = ((float)sv + bf2f(xW1s_bf[idx])) * INVFX * ic + b1[ch];
        float hv = fmaxf(v, 0.f) + xT1[idx];
        h[idx]     = hv;
        hs_bf[idx] = f2bf(hv * ic * FXS);  // pre-scaled for layer-2 accumulation
    }
}

// ---------------- agg2: bucket u64-LDS accumulate + fused 16->64 linears ---
__global__ __launch_bounds__(AGG_T) void agg2_bucket_kernel(
    const int* __restrict__ barr, const int* __restrict__ gcur,
    const float* __restrict__ inv, const int* __restrict__ deg,
    const unsigned short* __restrict__ hs_bf, const float* __restrict__ h,
    const float* __restrict__ W2, const float* __restrict__ T2,
    const float* __restrict__ b2, const float* __restrict__ t2b,
    float* __restrict__ out, int n)
{
    __shared__ unsigned long long acc[BNODES][ACC2P];   // 9216 B
    __shared__ float Wc[C1][128];          // 8 KB: [:,0:64]=W2, [:,64:128]=T2
    __shared__ float h_s[BNODES][C1];      // 8 KB: unscaled h for identity2
    __shared__ float accf[BNODES][C1 + 1]; // 8.7 KB: finalized aggregate
    int b = blockIdx.x, tid = threadIdx.x;
    for (int i = tid; i < BNODES * ACC2P; i += AGG_T) (&acc[0][0])[i] = 0ull;
    for (int i = tid; i < C1 * 128; i += AGG_T) {
        int k = i >> 7, c = i & 127;
        Wc[k][c] = (c < 64) ? W2[k * C2 + c] : T2[k * C2 + (c - 64)];
    }
    {   // stage h rows (contiguous across bucket -> coalesced float4)
        int node0 = b << LOCB;
        for (int t = tid; t < BNODES * C1 / 4; t += AGG_T) {
            float4 v = make_float4(0.f, 0.f, 0.f, 0.f);
            if (node0 + (t >> 2) < n) v = ((const float4*)h)[(size_t)node0 * 4 + t];
            ((float4*)&h_s[0][0])[t] = v;
        }
    }
    __syncthreads();

    int base = b * CAP;
    int len = gcur[b] - base;
    if (len < 0) len = 0;
    if (len > CAP) len = CAP;
    const int* bp = barr + base;
    unsigned un = (unsigned)n;
    int chb = (tid & 1) << 3;
    int tb  = (tid & 1) << 2;

    GATHER_SCATTER(hs_bf)
    __syncthreads();

    // finalize: de-bias, add self (same scale), unscale, *inv -> accf
    for (int t = tid; t < BNODES * C1; t += AGG_T) {
        int loc = t >> 4, ch = t & 15;
        int node = (b << LOCB) + loc;
        float v = 0.f;
        if (node < n) {
            unsigned long long w = acc[loc][ch >> 1];
            unsigned wd = (ch & 1) ? (unsigned)(w >> 32) : (unsigned)w;
            int sv = (int)(wd - ((unsigned)deg[node] << BSH));
            v = ((float)sv + bf2f(hs_bf[(node << 4) + ch])) * INVFX * inv[node];
        }
        accf[loc][ch] = v;
    }
    __syncthreads();

    // 16->64 matmuls: weights hoisted to registers, acc/h_s broadcast reads
    int och = tid & 63, g = tid >> 6;      // 8 groups x 16 locs
    float w1r[C1], w2r[C1];
    #pragma unroll
    for (int k = 0; k < C1; ++k) { w1r[k] = Wc[k][och]; w2r[k] = Wc[k][och + 64]; }
    float bb = b2[och], tb2 = t2b[och];
    for (int q = 0; q < 16; ++q) {
        int loc = (g << 4) + q;
        int node2 = (b << LOCB) + loc;
        if (node2 >= n) continue;
        float s1 = bb, s2 = tb2;
        #pragma unroll
        for (int k = 0; k < C1; ++k) {
            s1 += accf[loc][k] * w1r[k];
            s2 += h_s[loc][k]  * w2r[k];
        }
        out[(size_t)node2 * C2 + och] = fmaxf(s1, 0.f) + s2;
    }
}

extern "C" void kernel_launch(void* const* d_in, const int* in_sizes, int n_in,
                              void* d_out, int out_size, void* d_ws, size_t ws_size,
                              hipStream_t stream) {
    const float* x   = (const float*)d_in[0];
    const int*   ei  = (const int*)d_in[1];
    const float* W1  = (const float*)d_in[2];
    const float* b1  = (const float*)d_in[3];
    const float* W2  = (const float*)d_in[4];
    const float* b2  = (const float*)d_in[5];
    const float* T1  = (const float*)d_in[6];
    const float* t1b = (const float*)d_in[7];
    const float* T2  = (const float*)d_in[8];
    const float* t2b = (const float*)d_in[9];
    float* out = (float*)d_out;

    const int n = in_sizes[0] / INCH;       // 100000
    const int e = in_sizes[1] / 2;          // 3200000
    const int* row = ei;
    const int* col = ei + e;
    const int K = (n + BNODES - 1) >> LOCB; // 782 buckets

    // workspace layout
    char* ws = (char*)d_ws;
    int*   gcur  = (int*)ws;                          ws += 4096;
    float* inv   = (float*)ws;                        ws += (size_t)n * 4;
    int*   deg   = (int*)ws;                          ws += (size_t)n * 4;
    float* xT1   = (float*)ws;                        ws += (size_t)n * C1 * 4;
    float* h     = (float*)ws;                        ws += (size_t)n * C1 * 4;
    unsigned short* xW1s_bf = (unsigned short*)ws;    ws += (size_t)n * C1 * 2;
    unsigned short* hs_bf   = (unsigned short*)ws;    ws += (size_t)n * C1 * 2;
    int*   barr  = (int*)ws;                          ws += (size_t)K * CAP * 4; // 25.6 MB

    const int nbb = 390;     // bucket_kernel blocks

    binit_kernel  <<<(K + 255) / 256, 256, 0, stream>>>(gcur, K);
    bucket_kernel <<<nbb, BKT_T, 0, stream>>>(row, col, gcur, barr, e, n, K, nbb);
    degree_kernel <<<K, AGG_T, 0, stream>>>(barr, gcur, inv, deg, n);

    linear1_kernel <<<(n + 15) / 16, 256, 0, stream>>>(x, W1, T1, t1b, inv, xW1s_bf, xT1, n);
    agg1_bucket_kernel<<<K, AGG_T, 0, stream>>>(barr, gcur, inv, deg, xW1s_bf, xT1, b1, h, hs_bf, n);
    agg2_bucket_kernel<<<K, AGG_T, 0, stream>>>(barr, gcur, inv, deg, hs_bf, h,
                                                W2, T2, b2, t2b, out, n);
}